// Round 2
// baseline (341.898 us; speedup 1.0000x reference)
//
#include <hip/hip_runtime.h>
#include <stdint.h>

typedef __bf16 bf16_t;
typedef __bf16 bf16x8 __attribute__((ext_vector_type(8)));
typedef __bf16 bf16x4 __attribute__((ext_vector_type(4)));
typedef float floatx4 __attribute__((ext_vector_type(4)));

#define AS3(p) ((__attribute__((address_space(3))) void*)(p))
#define AS1(p) ((__attribute__((address_space(1))) void*)(void*)(p))

// ---------- convert f32 -> bf16, flat ----------
__global__ __launch_bounds__(256) void cvt_k(const float* __restrict__ src,
                                             bf16_t* __restrict__ dst, int n) {
  const int i = (blockIdx.x * 256 + threadIdx.x) * 8;
  if (i + 8 <= n) {
    floatx4 a = *(const floatx4*)&src[i];
    floatx4 b = *(const floatx4*)&src[i + 4];
    bf16x8 o;
#pragma unroll
    for (int j = 0; j < 4; ++j) { o[j] = (bf16_t)a[j]; o[4 + j] = (bf16_t)b[j]; }
    *(bf16x8*)&dst[i] = o;
  }
}

// ---------- transpose + convert: dst[n][k] = (bf16)src[k][n]; src f32 [2048][ncols] ----------
__global__ __launch_bounds__(256) void tr_k(const float* __restrict__ src, int ncols,
                                            bf16_t* __restrict__ dst) {
  __shared__ __align__(16) bf16_t T[64][68];
  const int t = threadIdx.x;
  const int nt = blockIdx.x * 64, kt = blockIdx.y * 64;
  const int r0 = t >> 4;          // 0..15
  const int c0 = (t & 15) << 2;   // 0..60
#pragma unroll
  for (int p = 0; p < 4; ++p) {
    const int row = p * 16 + r0;
    floatx4 v = *(const floatx4*)&src[(size_t)(kt + row) * ncols + nt + c0];
    bf16x4 b;
#pragma unroll
    for (int i = 0; i < 4; ++i) b[i] = (bf16_t)v[i];
    *(bf16x4*)&T[row][c0] = b;
  }
  __syncthreads();
#pragma unroll
  for (int p = 0; p < 4; ++p) {
    const int n = p * 16 + r0;
    bf16x4 tmp;
#pragma unroll
    for (int i = 0; i < 4; ++i) tmp[i] = T[c0 + i][n];
    *(bf16x4*)&dst[(size_t)(nt + n) * 2048 + kt + c0] = tmp;
  }
}

// ---------- GEMM: C[m][n] = sum_k A[m][k] * Bt[n][k], K=2048, A/Bt bf16 ----------
// EPI 0: QKV epilogue (RoPE on q/k, transpose-scatter v), bf16 outputs.
// EPI 1: plain f32 store to fo.
template <int EPI>
__global__ __launch_bounds__(256) void gemm_k(const bf16_t* __restrict__ A,
                                              const bf16_t* __restrict__ Bt,
                                              bf16_t* __restrict__ o0,
                                              bf16_t* __restrict__ o1,
                                              bf16_t* __restrict__ o2,
                                              float* __restrict__ fo,
                                              const float* __restrict__ fcos,
                                              const float* __restrict__ fsin) {
  constexpr int K = 2048;
  __shared__ __align__(16) bf16_t As[128 * 64];
  __shared__ __align__(16) bf16_t Bs[128 * 64];
  const int tid = threadIdx.x;
  const int lane = tid & 63;
  const int w = tid >> 6;
  const int quad = lane >> 4;
  const int l15 = lane & 15;
  const int m0 = blockIdx.y * 128;
  const int n0 = blockIdx.x * 128;
  const int wm = (w & 1) * 64;
  const int wn = (w >> 1) * 64;
  const int srow = lane >> 3;        // 0..7
  const int scol = (lane & 7) << 3;  // 0..56
  floatx4 acc[4][4] = {};

  for (int k0 = 0; k0 < K; k0 += 64) {
#pragma unroll
    for (int j = 0; j < 4; ++j) {
      const int row = j * 32 + w * 8 + srow;
      const bf16_t* ga = A + (size_t)(m0 + row) * K + k0 + scol;
      const bf16_t* gb = Bt + (size_t)(n0 + row) * K + k0 + scol;
      __builtin_amdgcn_global_load_lds(AS1(ga), AS3(&As[(j * 32 + w * 8) * 64]), 16, 0, 0);
      __builtin_amdgcn_global_load_lds(AS1(gb), AS3(&Bs[(j * 32 + w * 8) * 64]), 16, 0, 0);
    }
    __syncthreads();
#pragma unroll
    for (int kk = 0; kk < 2; ++kk) {
      bf16x8 af[4], bfr[4];
#pragma unroll
      for (int i = 0; i < 4; ++i) {
        af[i] = *(const bf16x8*)&As[(wm + i * 16 + l15) * 64 + kk * 32 + quad * 8];
        bfr[i] = *(const bf16x8*)&Bs[(wn + i * 16 + l15) * 64 + kk * 32 + quad * 8];
      }
#pragma unroll
      for (int mi = 0; mi < 4; ++mi)
#pragma unroll
        for (int ni = 0; ni < 4; ++ni)
          acc[mi][ni] =
              __builtin_amdgcn_mfma_f32_16x16x32_bf16(af[mi], bfr[ni], acc[mi][ni], 0, 0, 0);
    }
    __syncthreads();
  }

  if constexpr (EPI == 0) {
    // cols [0,2048): q -> o0[s][2048] with RoPE; [2048,2560): k -> o1[s][512] with RoPE;
    // [2560,3072): v -> o2[(col-2560)][s] (transposed), no RoPE.
#pragma unroll
    for (int ni = 0; ni < 4; ++ni) {
      const int col = n0 + wn + ni * 16 + l15;
#pragma unroll
      for (int mi = 0; mi < 4; ++mi) {
        const int sb = m0 + wm + mi * 16 + quad * 4;
        if (col < 2560) {  // uniform per wave (boundaries are multiples of 16)
          const int fi = (col & 63) >> 1;
#pragma unroll
          for (int r = 0; r < 4; ++r) {
            const float v = acc[mi][ni][r];
            const float prt = __shfl_xor(v, 1);  // partner column within rope pair
            const int s = sb + r;
            const float c = fcos[s * 32 + fi];
            const float sn = fsin[s * 32 + fi];
            const float ov = (col & 1) ? (prt * sn + v * c) : (v * c - prt * sn);
            if (col < 2048)
              o0[(size_t)s * 2048 + col] = (bf16_t)ov;
            else
              o1[(size_t)s * 512 + (col - 2048)] = (bf16_t)ov;
          }
        } else {
          bf16x4 pv;
#pragma unroll
          for (int r = 0; r < 4; ++r) pv[r] = (bf16_t)acc[mi][ni][r];
          *(bf16x4*)&o2[(size_t)(col - 2560) * 2048 + sb] = pv;
        }
      }
    }
  } else {
#pragma unroll
    for (int ni = 0; ni < 4; ++ni) {
      const int col = n0 + wn + ni * 16 + l15;
#pragma unroll
      for (int mi = 0; mi < 4; ++mi) {
        const int sb = m0 + wm + mi * 16 + quad * 4;
#pragma unroll
        for (int r = 0; r < 4; ++r) fo[(size_t)(sb + r) * 2048 + col] = acc[mi][ni][r];
      }
    }
  }
}

// ---------- flash attention, S^T formulation ----------
// qb_: [2048][2048] (s, h*64+d). kb_: [2048][512]. vt_: [512][2048] (g*64+d, s).
// ob_: [2048][2048]. Block = (64 queries) x (1 head); wave = 16 queries.
__global__ __launch_bounds__(256) void attn_k(const bf16_t* __restrict__ qb_,
                                              const bf16_t* __restrict__ kb_,
                                              const bf16_t* __restrict__ vt_,
                                              bf16_t* __restrict__ ob_) {
  const int lane = threadIdx.x & 63, w = threadIdx.x >> 6;
  const int quad = lane >> 4, l15 = lane & 15;
  const int h = blockIdx.y, g = h >> 2;
  const int qb = blockIdx.x * 64;
  const int q = qb + w * 16 + l15;  // this lane's query column
  const bf16_t* qrow = qb_ + (size_t)q * 2048 + h * 64;
  const bf16x8 qf0 = *(const bf16x8*)(qrow + quad * 8);
  const bf16x8 qf1 = *(const bf16x8*)(qrow + 32 + quad * 8);
  float m_run = -3.0e38f, l_run = 0.f;
  floatx4 acc[4] = {};  // O^T: acc[dblk][r] -> d = dblk*16 + quad*4 + r, col q
  const float SC = 0.125f * 1.44269504088896340736f;  // scale * log2(e)
  const int kstart = (qb >= 1024) ? (qb - 1024) : 0;

  for (int kb = kstart; kb < qb + 64; kb += 32) {
    float p[2][4];
    float tmax = -3.0e38f;
#pragma unroll
    for (int t = 0; t < 2; ++t) {
      const bf16_t* kr = kb_ + (size_t)(kb + t * 16 + l15) * 512 + g * 64;
      const bf16x8 kf0 = *(const bf16x8*)(kr + quad * 8);
      const bf16x8 kf1 = *(const bf16x8*)(kr + 32 + quad * 8);
      floatx4 z = {};
      z = __builtin_amdgcn_mfma_f32_16x16x32_bf16(kf0, qf0, z, 0, 0, 0);
      z = __builtin_amdgcn_mfma_f32_16x16x32_bf16(kf1, qf1, z, 0, 0, 0);
#pragma unroll
      for (int r = 0; r < 4; ++r) {
        const int key = kb + t * 16 + quad * 4 + r;
        const bool ok = (key <= q) && (key + 1024 >= q);
        const float sv = ok ? z[r] * SC : -3.0e38f;
        p[t][r] = sv;
        tmax = fmaxf(tmax, sv);
      }
    }
    tmax = fmaxf(tmax, __shfl_xor(tmax, 16));
    tmax = fmaxf(tmax, __shfl_xor(tmax, 32));
    const float m_new = fmaxf(m_run, tmax);
    const float alpha = exp2f(m_run - m_new);
    m_run = m_new;
    float psum = 0.f;
#pragma unroll
    for (int t = 0; t < 2; ++t)
#pragma unroll
      for (int r = 0; r < 4; ++r) {
        const float pe = (p[t][r] > -1.0e37f) ? exp2f(p[t][r] - m_new) : 0.f;
        p[t][r] = pe;
        psum += pe;
      }
    psum += __shfl_xor(psum, 16);
    psum += __shfl_xor(psum, 32);
    l_run = l_run * alpha + psum;
#pragma unroll
    for (int d = 0; d < 4; ++d) acc[d] *= alpha;
    // Build P^T B-fragment: lane wants p(key32 = quad*8+i, q=l15)
    bf16x8 pf;
#pragma unroll
    for (int i = 0; i < 8; ++i) {
      const int srcl = ((quad & 1) * 2 + (i >> 2)) * 16 + l15;
      const float v0 = __shfl(p[0][i & 3], srcl);
      const float v1 = __shfl(p[1][i & 3], srcl);
      pf[i] = (bf16_t)((quad & 2) ? v1 : v0);
    }
#pragma unroll
    for (int d = 0; d < 4; ++d) {
      const bf16x8 vf =
          *(const bf16x8*)&vt_[(size_t)(g * 64 + d * 16 + l15) * 2048 + kb + quad * 8];
      acc[d] = __builtin_amdgcn_mfma_f32_16x16x32_bf16(vf, pf, acc[d], 0, 0, 0);
    }
  }
  const float inv = 1.f / l_run;
#pragma unroll
  for (int d = 0; d < 4; ++d) {
    bf16x4 ov;
#pragma unroll
    for (int r = 0; r < 4; ++r) ov[r] = (bf16_t)(acc[d][r] * inv);
    *(bf16x4*)&ob_[(size_t)q * 2048 + h * 64 + d * 16 + quad * 4] = ov;
  }
}

extern "C" void kernel_launch(void* const* d_in, const int* in_sizes, int n_in, void* d_out,
                              int out_size, void* d_ws, size_t ws_size, hipStream_t stream) {
  (void)in_sizes;
  (void)n_in;
  (void)out_size;
  (void)ws_size;
  const float* x = (const float*)d_in[0];
  const float* wq = (const float*)d_in[1];
  const float* wk = (const float*)d_in[2];
  const float* wv = (const float*)d_in[3];
  const float* wo = (const float*)d_in[4];
  const float* fcos = (const float*)d_in[5];
  const float* fsin = (const float*)d_in[6];
  float* out = (float*)d_out;

  // ws layout (bf16 elems): xb[2048*2048] | wt[5120*2048] | q[2048*2048] | k[2048*512]
  //                         | vt[512*2048] | att[2048*2048]   (~50 MB)
  bf16_t* xb = (bf16_t*)d_ws;
  bf16_t* wt = xb + (size_t)2048 * 2048;
  bf16_t* qbuf = wt + (size_t)5120 * 2048;
  bf16_t* kbuf = qbuf + (size_t)2048 * 2048;
  bf16_t* vtb = kbuf + (size_t)2048 * 512;
  bf16_t* att = vtb + (size_t)512 * 2048;

  cvt_k<<<2048, 256, 0, stream>>>(x, xb, 2048 * 2048);
  tr_k<<<dim3(32, 32), 256, 0, stream>>>(wq, 2048, wt);
  tr_k<<<dim3(8, 32), 256, 0, stream>>>(wk, 512, wt + (size_t)2048 * 2048);
  tr_k<<<dim3(8, 32), 256, 0, stream>>>(wv, 512, wt + (size_t)2560 * 2048);
  tr_k<<<dim3(32, 32), 256, 0, stream>>>(wo, 2048, wt + (size_t)3072 * 2048);
  gemm_k<0><<<dim3(24, 16), 256, 0, stream>>>(xb, wt, qbuf, kbuf, vtb, nullptr, fcos, fsin);
  attn_k<<<dim3(32, 32), 256, 0, stream>>>(qbuf, kbuf, vtb, att);
  gemm_k<1><<<dim3(16, 16), 256, 0, stream>>>(att, wt + (size_t)3072 * 2048, nullptr, nullptr,
                                              nullptr, out, fcos, fsin);
}